// Round 1
// baseline (33394.946 us; speedup 1.0000x reference)
//
#include <hip/hip_runtime.h>
#include <hip/hip_cooperative_groups.h>

namespace cg = cooperative_groups;

// ws layout (floats):
#define H1_OFF   0          // [2][512][64]  h1 double buffer, transposed [k][b]
#define H2_OFF   65536      // [2][512][64]
#define XT_OFF   131072     // [512][64]     x transposed [t][b]
#define WT1_OFF  163840     // [2048][512]   W0 recurrent, col-major
#define WT2A_OFF (163840 + 1048576)   // [2048][512] W1 rows 0..511 (h1 input)
#define WT2B_OFF (163840 + 2097152)   // [2048][512] W1 rows 512..1023 (h2 recur)

__device__ __forceinline__ float sigm(float x) { return 1.f / (1.f + __expf(-x)); }
__device__ __forceinline__ float tanh_f(float x) {
    float a = fabsf(x);
    float e = __expf(-2.f * a);
    float r = (1.f - e) / (1.f + e);
    return copysignf(r, x);
}

__global__ void init_kernel(const float* __restrict__ x, const float* __restrict__ W0,
                            const float* __restrict__ W1, float* __restrict__ ws) {
    int i = blockIdx.x * blockDim.x + threadIdx.x;
    int stride = gridDim.x * blockDim.x;
    // zero h double-buffers (phase 0/1 read zero state)
    for (int j = i; j < 131072; j += stride) ws[j] = 0.f;
    // transpose x [64][512] -> xT [512][64]
    for (int j = i; j < 32768; j += stride) {
        int p = j >> 6, b = j & 63;
        ws[XT_OFF + j] = x[b * 512 + p];
    }
    // transpose weights to column-major (coalesced reads, scattered writes)
    for (int j = i; j < 1048576; j += stride) {
        int c = j & 2047, k = j >> 11;
        ws[WT1_OFF  + c * 512 + k] = W0[(1 + k) * 2048 + c];
        ws[WT2A_OFF + c * 512 + k] = W1[k * 2048 + c];
        ws[WT2B_OFF + c * 512 + k] = W1[(512 + k) * 2048 + c];
    }
}

__global__ __launch_bounds__(512) void lstm_kernel(float* __restrict__ ws,
        const float* __restrict__ W0, const float* __restrict__ b0,
        const float* __restrict__ b1) {
    cg::grid_group grid = cg::this_grid();
    __shared__ float zb1[512], zb2[512], c1s[128], c2s[128];

    const int t = threadIdx.x, bx = blockIdx.x;  // bx in 0..255
    const int b = t & 63;
    int q = __builtin_amdgcn_readfirstlane((t >> 6) & 7);  // wave-uniform
    const int g = q >> 1, hu = q & 1;
    const int col = g * 512 + (bx * 2 + hu);  // gate column in [0,2048)

    float* H1 = ws + H1_OFF;
    float* H2 = ws + H2_OFF;
    const float* xT = ws + XT_OFF;
    const float4* w1q  = (const float4*)(ws + WT1_OFF  + col * 512);
    const float4* w2aq = (const float4*)(ws + WT2A_OFF + col * 512);
    const float4* w2bq = (const float4*)(ws + WT2B_OFF + col * 512);
    const float w0xc = W0[col];   // W0 row 0 (scalar input weight)
    const float b0c = b0[col], b1c = b1[col];

    if (t < 128) { c1s[t] = 0.f; c2s[t] = 0.f; }
    __syncthreads();

    for (int p = 0; p <= 512; ++p) {
        const float* h1o = H1 + (p & 1) * 32768;   // h1[p-1], [k][b]
        const float* h2o = H2 + (p & 1) * 32768;   // h2[p-2]
        float a10 = 0, a11 = 0, a12 = 0, a13 = 0;
        float a20 = 0, a21 = 0, a22 = 0, a23 = 0;
        for (int k4 = 0; k4 < 128; ++k4) {
            float4 w1v = w1q[k4], w2av = w2aq[k4], w2bv = w2bq[k4];  // s_load (uniform)
            int base = k4 * 256 + b;
            float h10 = h1o[base], h11 = h1o[base + 64], h12 = h1o[base + 128], h13 = h1o[base + 192];
            float h20 = h2o[base], h21 = h2o[base + 64], h22 = h2o[base + 128], h23 = h2o[base + 192];
            a10 += h10 * w1v.x; a11 += h11 * w1v.y; a12 += h12 * w1v.z; a13 += h13 * w1v.w;
            a20 += h10 * w2av.x + h20 * w2bv.x;
            a21 += h11 * w2av.y + h21 * w2bv.y;
            a22 += h12 * w2av.z + h22 * w2bv.z;
            a23 += h13 * w2av.w + h23 * w2bv.w;
        }
        float xv = (p < 512) ? xT[p * 64 + b] : 0.f;
        zb1[q * 64 + b] = (a10 + a11) + (a12 + a13) + xv * w0xc + b0c;
        zb2[q * 64 + b] = (a20 + a21) + (a22 + a23) + b1c;
        __syncthreads();
        if (t < 128) {
            if (p < 512) {  // layer1 update for step p
                int huu = t >> 6, bb = t & 63;
                float iv = zb1[huu * 64 + bb];
                float jv = zb1[(2 + huu) * 64 + bb];
                float fv = zb1[(4 + huu) * 64 + bb];
                float ov = zb1[(6 + huu) * 64 + bb];
                float c = c1s[t];
                c = c * sigm(fv + 1.f) + sigm(iv) * tanh_f(jv);
                c1s[t] = c;
                (H1 + ((p + 1) & 1) * 32768)[(bx * 2 + huu) * 64 + bb] = tanh_f(c) * sigm(ov);
            }
        } else if (t < 256) {
            if (p >= 1) {   // layer2 update for step p-1
                int huu = (t - 128) >> 6, bb = t & 63;
                float iv = zb2[huu * 64 + bb];
                float jv = zb2[(2 + huu) * 64 + bb];
                float fv = zb2[(4 + huu) * 64 + bb];
                float ov = zb2[(6 + huu) * 64 + bb];
                float c = c2s[t - 128];
                c = c * sigm(fv + 1.f) + sigm(iv) * tanh_f(jv);
                c2s[t - 128] = c;
                (H2 + ((p + 1) & 1) * 32768)[(bx * 2 + huu) * 64 + bb] = tanh_f(c) * sigm(ov);
            }
        }
        grid.sync();
    }
    // final h2[511] lives in H2[1] (written at phase 512)
}

__global__ void logits_kernel(const float* __restrict__ ws, const float* __restrict__ sw,
                              const float* __restrict__ sb, float* __restrict__ out) {
    const float* h2 = ws + H2_OFF + 32768;  // H2[1] = h2[T-1], [k][b]
    int c = blockIdx.x, b = threadIdx.x;
    float acc = 0.f;
    for (int k = 0; k < 512; ++k) acc += h2[k * 64 + b] * sw[k * 10 + c];
    out[b * 10 + c] = acc + sb[c];
}

extern "C" void kernel_launch(void* const* d_in, const int* in_sizes, int n_in,
                              void* d_out, int out_size, void* d_ws, size_t ws_size,
                              hipStream_t stream) {
    (void)in_sizes; (void)n_in; (void)out_size; (void)ws_size;
    const float* x  = (const float*)d_in[0];
    const float* W0 = (const float*)d_in[1];
    const float* b0 = (const float*)d_in[2];
    const float* W1 = (const float*)d_in[3];
    const float* b1 = (const float*)d_in[4];
    const float* sw = (const float*)d_in[5];
    const float* sb = (const float*)d_in[6];
    float* ws  = (float*)d_ws;
    float* out = (float*)d_out;

    hipLaunchKernelGGL(init_kernel, dim3(1024), dim3(256), 0, stream, x, W0, W1, ws);

    float* ws_p = ws;
    const float* W0_p = W0;
    const float* b0_p = b0;
    const float* b1_p = b1;
    void* args[] = { &ws_p, &W0_p, &b0_p, &b1_p };
    hipLaunchCooperativeKernel((void*)lstm_kernel, dim3(256), dim3(512), args, 0, stream);

    hipLaunchKernelGGL(logits_kernel, dim3(10), dim3(64), 0, stream, ws, sw, sb, out);
}

// Round 2
// 26733.026 us; speedup vs baseline: 1.2492x; 1.2492x over previous
//
#include <hip/hip_runtime.h>
#include <hip/hip_bf16.h>
#include <hip/hip_cooperative_groups.h>

namespace cg = cooperative_groups;

// ws byte layout:
//   H1: bf16 [2][512][64]   @ 0         (131072 B)  h1 double buffer, [unit k][batch b]
//   H2: bf16 [2][512][64]   @ 131072    (131072 B)
//   XT: f32  [512][64]      @ 262144    (131072 B)  x transposed [t][b]
//   WP: f32  [256][512][24] @ 393216    (12.6 MB)   per-WG packed weights:
//        WP[bx][k][c]  c=0..7: W0r col(c); 8..15: W1a col(c); 16..23: W1b col(c)
//        col(c) = (c>>1)*512 + bx*2 + (c&1)   (c = gate*2 + hu)
#define H1_BYTES 0
#define H2_BYTES 131072
#define XT_BYTES 262144
#define WP_BYTES 393216

__device__ __forceinline__ float sigm(float x) { return 1.f / (1.f + __expf(-x)); }
__device__ __forceinline__ float tanh_f(float x) {
    float a = fabsf(x);
    float e = __expf(-2.f * a);
    float r = (1.f - e) / (1.f + e);
    return copysignf(r, x);
}

__global__ void init_kernel(const float* __restrict__ x, const float* __restrict__ W0,
                            const float* __restrict__ W1, char* __restrict__ wsb) {
    unsigned short* Hz = (unsigned short*)(wsb + H1_BYTES);   // H1+H2, 131072 bf16
    float* XT = (float*)(wsb + XT_BYTES);
    float* WP = (float*)(wsb + WP_BYTES);
    int i = blockIdx.x * blockDim.x + threadIdx.x;
    int stride = gridDim.x * blockDim.x;
    for (int j = i; j < 131072; j += stride) Hz[j] = 0;      // zero h1/h2 (both buffers)
    for (int j = i; j < 32768; j += stride) {
        int p = j >> 6, b = j & 63;
        XT[j] = x[b * 512 + p];
    }
    for (int j = i; j < 256 * 512 * 24; j += stride) {
        int c = j % 24;
        int r = j / 24;            // bx*512 + k
        int k = r & 511;
        int bx = r >> 9;
        int cc = c & 7;
        int col = ((cc >> 1) << 9) + bx * 2 + (cc & 1);
        int mat = c >> 3;
        float v;
        if (mat == 0)      v = W0[(1 + k) * 2048 + col];
        else if (mat == 1) v = W1[k * 2048 + col];
        else               v = W1[(512 + k) * 2048 + col];
        WP[j] = v;
    }
}

__global__ __launch_bounds__(512) void lstm_kernel(char* __restrict__ wsb,
        const float* __restrict__ W0, const float* __restrict__ b0,
        const float* __restrict__ b1) {
    cg::grid_group grid = cg::this_grid();
    __shared__ float red[2][8][8][64];   // [layer][wave][c][b], 32 KB

    const int t = threadIdx.x, bx = blockIdx.x;
    const int b = t & 63;
    const int w = __builtin_amdgcn_readfirstlane(t >> 6);    // wave id, k-slice owner

    const __hip_bfloat16* H1 = (const __hip_bfloat16*)(wsb + H1_BYTES);
    const __hip_bfloat16* H2 = (const __hip_bfloat16*)(wsb + H2_BYTES);
    __hip_bfloat16* H1w = (__hip_bfloat16*)(wsb + H1_BYTES);
    __hip_bfloat16* H2w = (__hip_bfloat16*)(wsb + H2_BYTES);
    const float* XT = (const float*)(wsb + XT_BYTES);
    const float* wp = (const float*)(wsb + WP_BYTES)
                    + __builtin_amdgcn_readfirstlane(bx * 12288 + (t >> 6) * 64 * 24);

    // cell-update threads: t<256 -> (layer, hu, b); c-state lives in a register
    const int cell_l = t >> 7, cell_hu = (t >> 6) & 1;
    float cstate = 0.f;
    float bias_i = 0, bias_j = 0, bias_f = 0, bias_o = 0;
    float wx_i = 0, wx_j = 0, wx_f = 0, wx_o = 0;
    if (t < 256) {
        int u = bx * 2 + cell_hu;
        const float* bb = (cell_l == 0) ? b0 : b1;
        bias_i = bb[0 * 512 + u]; bias_j = bb[1 * 512 + u];
        bias_f = bb[2 * 512 + u]; bias_o = bb[3 * 512 + u];
        if (cell_l == 0) {  // W0 row 0 = scalar-input weights
            wx_i = W0[0 * 512 + u]; wx_j = W0[1 * 512 + u];
            wx_f = W0[2 * 512 + u]; wx_o = W0[3 * 512 + u];
        }
    }

    for (int p = 0; p <= 512; ++p) {
        const __hip_bfloat16* h1p = H1 + (p & 1) * 32768 + w * 64 * 64 + b;
        const __hip_bfloat16* h2p = H2 + (p & 1) * 32768 + w * 64 * 64 + b;
        float p1[8] = {0, 0, 0, 0, 0, 0, 0, 0};
        float p2[8] = {0, 0, 0, 0, 0, 0, 0, 0};
        #pragma unroll 4
        for (int k = 0; k < 64; ++k) {
            float h1v = __bfloat162float(h1p[k * 64]);
            float h2v = __bfloat162float(h2p[k * 64]);
            const float* wk = wp + k * 24;    // wave-uniform -> s_load
            #pragma unroll
            for (int c = 0; c < 8; ++c) {
                p1[c] += wk[c] * h1v;
                p2[c] += wk[8 + c] * h1v + wk[16 + c] * h2v;
            }
        }
        #pragma unroll
        for (int c = 0; c < 8; ++c) {
            red[0][w][c][b] = p1[c];
            red[1][w][c][b] = p2[c];
        }
        float xv = (t < 128 && p < 512) ? XT[p * 64 + b] : 0.f;
        __syncthreads();
        if (t < 256) {
            bool active = (cell_l == 0) ? (p < 512) : (p >= 1);
            if (active) {
                const int c_i = cell_hu, c_j = 2 + cell_hu, c_f = 4 + cell_hu, c_o = 6 + cell_hu;
                float zi = bias_i, zj = bias_j, zf = bias_f, zo = bias_o;
                #pragma unroll
                for (int ww = 0; ww < 8; ++ww) {
                    zi += red[cell_l][ww][c_i][b];
                    zj += red[cell_l][ww][c_j][b];
                    zf += red[cell_l][ww][c_f][b];
                    zo += red[cell_l][ww][c_o][b];
                }
                if (cell_l == 0) {
                    zi += xv * wx_i; zj += xv * wx_j; zf += xv * wx_f; zo += xv * wx_o;
                }
                float c = cstate;
                c = c * sigm(zf + 1.f) + sigm(zi) * tanh_f(zj);
                cstate = c;
                float hn = tanh_f(c) * sigm(zo);
                __hip_bfloat16* Hn = (cell_l == 0 ? H1w : H2w) + ((p + 1) & 1) * 32768;
                Hn[(bx * 2 + cell_hu) * 64 + b] = __float2bfloat16(hn);
            }
        }
        grid.sync();
    }
}

__global__ void logits_kernel(const char* __restrict__ wsb, const float* __restrict__ sw,
                              const float* __restrict__ sb, float* __restrict__ out) {
    const __hip_bfloat16* h2 = (const __hip_bfloat16*)(wsb + H2_BYTES) + 32768; // H2[1]=h2[T-1]
    int c = blockIdx.x, b = threadIdx.x;
    float acc = 0.f;
    for (int k = 0; k < 512; ++k) acc += __bfloat162float(h2[k * 64 + b]) * sw[k * 10 + c];
    out[b * 10 + c] = acc + sb[c];
}

extern "C" void kernel_launch(void* const* d_in, const int* in_sizes, int n_in,
                              void* d_out, int out_size, void* d_ws, size_t ws_size,
                              hipStream_t stream) {
    (void)in_sizes; (void)n_in; (void)out_size; (void)ws_size;
    const float* x  = (const float*)d_in[0];
    const float* W0 = (const float*)d_in[1];
    const float* b0 = (const float*)d_in[2];
    const float* W1 = (const float*)d_in[3];
    const float* b1 = (const float*)d_in[4];
    const float* sw = (const float*)d_in[5];
    const float* sb = (const float*)d_in[6];
    char* wsb  = (char*)d_ws;
    float* out = (float*)d_out;

    hipLaunchKernelGGL(init_kernel, dim3(1024), dim3(256), 0, stream, x, W0, W1, wsb);

    char* wsb_p = wsb;
    const float* W0_p = W0;
    const float* b0_p = b0;
    const float* b1_p = b1;
    void* args[] = { &wsb_p, &W0_p, &b0_p, &b1_p };
    hipLaunchCooperativeKernel((void*)lstm_kernel, dim3(256), dim3(512), args, 0, stream);

    hipLaunchKernelGGL(logits_kernel, dim3(10), dim3(64), 0, stream, wsb, sw, sb, out);
}

// Round 4
// 17988.547 us; speedup vs baseline: 1.8565x; 1.4861x over previous
//
#include <hip/hip_runtime.h>
#include <hip/hip_bf16.h>

// ws byte layout:
//   H1:  bf16 [2][256][64][2] @ 0       (131072 B)  h1 dbuf, [k/2][batch][k&1] pairs
//   H2:  bf16 [2][256][64][2] @ 131072  (131072 B)
//   XT:  bf16 [512][64]       @ 262144  (65536 B)   x transposed [t][b]
//   BAR: int  leaf[16] @ stride 128 B, root @ +2048  @ 327680
//   WP:  f32  [256][512][24]  @ 393216  (12.6 MB)   per-WG packed weights
//        WP[bx][k][c]  c=0..7: W0r col(c); 8..15: W1a col(c); 16..23: W1b col(c)
//        col(c) = (c>>1)*512 + bx*2 + (c&1)
#define H1_BYTES 0
#define H2_BYTES 131072
#define XT_BYTES 262144
#define BAR_BYTES 327680
#define WP_BYTES 393216

__device__ __forceinline__ float sigm(float x) { return 1.f / (1.f + __expf(-x)); }
__device__ __forceinline__ float tanh_f(float x) {
    float a = fabsf(x);
    float e = __expf(-2.f * a);
    float r = (1.f - e) / (1.f + e);
    return copysignf(r, x);
}
__device__ __forceinline__ float bf2f(unsigned short u) {
    union { unsigned int i; float f; } v; v.i = (unsigned int)u << 16; return v.f;
}
__device__ __forceinline__ unsigned short f2bf(float f) {
    union { float f; unsigned int i; } v; v.f = f;
    unsigned int u = v.i + 0x7fffu + ((v.i >> 16) & 1u);   // RNE
    return (unsigned short)(u >> 16);
}

__global__ void init_kernel(const float* __restrict__ x, const float* __restrict__ W0,
                            const float* __restrict__ W1, char* __restrict__ wsb) {
    unsigned short* Hz = (unsigned short*)(wsb + H1_BYTES);   // H1+H2 = 131072 bf16
    unsigned short* XT = (unsigned short*)(wsb + XT_BYTES);
    int* BAR = (int*)(wsb + BAR_BYTES);
    float* WP = (float*)(wsb + WP_BYTES);
    int i = blockIdx.x * blockDim.x + threadIdx.x;
    int stride = gridDim.x * blockDim.x;
    for (int j = i; j < 131072; j += stride) Hz[j] = 0;
    for (int j = i; j < 32768; j += stride) {
        int p = j >> 6, b = j & 63;
        XT[j] = f2bf(x[b * 512 + p]);
    }
    for (int j = i; j < 17 * 32; j += stride) BAR[j] = 0;
    for (int j = i; j < 256 * 512 * 24; j += stride) {
        int c = j % 24;
        int r = j / 24;            // bx*512 + k
        int k = r & 511;
        int bx = r >> 9;
        int cc = c & 7;
        int col = ((cc >> 1) << 9) + bx * 2 + (cc & 1);
        int mat = c >> 3;
        float v;
        if (mat == 0)      v = W0[(1 + k) * 2048 + col];
        else if (mat == 1) v = W1[k * 2048 + col];
        else               v = W1[(512 + k) * 2048 + col];
        WP[j] = v;
    }
}

__device__ __forceinline__ void grid_bar(int* bar, int phase, int bx, int t) {
    __syncthreads();
    if (t == 0) {
        __threadfence();   // release this WG's h-writes
        int* leaf = bar + (bx >> 4) * 32;
        int* root = bar + 16 * 32;
        int target = (phase + 1) * 16;
        int old = __hip_atomic_fetch_add(leaf, 1, __ATOMIC_RELAXED, __HIP_MEMORY_SCOPE_AGENT);
        if (old == target - 1)
            __hip_atomic_fetch_add(root, 1, __ATOMIC_RELAXED, __HIP_MEMORY_SCOPE_AGENT);
        while (__hip_atomic_load(root, __ATOMIC_RELAXED, __HIP_MEMORY_SCOPE_AGENT) < target)
            __builtin_amdgcn_s_sleep(1);
        __threadfence();   // acquire: invalidate stale h lines
    }
    __syncthreads();
}

__global__ __launch_bounds__(512) void lstm_kernel(char* __restrict__ wsb,
        const float* __restrict__ W0, const float* __restrict__ b0,
        const float* __restrict__ b1) {
    __shared__ float red[2][8][8][64];   // [layer][wave][c][b], 32 KB

    const int t = threadIdx.x, bx = blockIdx.x;
    const int b = t & 63;
    const int w = __builtin_amdgcn_readfirstlane(t >> 6);    // wave id = k-slice owner

    const ushort2* H1r = (const ushort2*)(wsb + H1_BYTES);   // [2][256][64] pairs
    const ushort2* H2r = (const ushort2*)(wsb + H2_BYTES);
    unsigned short* H1w = (unsigned short*)(wsb + H1_BYTES);
    unsigned short* H2w = (unsigned short*)(wsb + H2_BYTES);
    const unsigned short* XT = (const unsigned short*)(wsb + XT_BYTES);
    int* BAR = (int*)(wsb + BAR_BYTES);
    const float* wp = (const float*)(wsb + WP_BYTES)
                    + __builtin_amdgcn_readfirstlane(bx * 12288 + (t >> 6) * 1536);

    const int cell_l = t >> 7, cell_hu = (t >> 6) & 1;
    float cstate = 0.f;
    float bias_i = 0, bias_j = 0, bias_f = 0, bias_o = 0;
    float wx_i = 0, wx_j = 0, wx_f = 0, wx_o = 0;
    if (t < 256) {
        int u = bx * 2 + cell_hu;
        const float* bb = (cell_l == 0) ? b0 : b1;
        bias_i = bb[0 * 512 + u]; bias_j = bb[1 * 512 + u];
        bias_f = bb[2 * 512 + u]; bias_o = bb[3 * 512 + u];
        if (cell_l == 0) {
            wx_i = W0[0 * 512 + u]; wx_j = W0[1 * 512 + u];
            wx_f = W0[2 * 512 + u]; wx_o = W0[3 * 512 + u];
        }
    }

    for (int p = 0; p <= 512; ++p) {
        const ushort2* h1p = H1r + (p & 1) * 16384 + w * 2048 + b;  // k2 = w*32 + loc
        const ushort2* h2p = H2r + (p & 1) * 16384 + w * 2048 + b;
        float p1[8] = {0, 0, 0, 0, 0, 0, 0, 0};
        float p2[8] = {0, 0, 0, 0, 0, 0, 0, 0};
        #pragma unroll 4
        for (int loc = 0; loc < 32; ++loc) {
            ushort2 u1 = h1p[loc * 64];
            ushort2 u2 = h2p[loc * 64];
            float h1a = bf2f(u1.x), h1b = bf2f(u1.y);
            float h2a = bf2f(u2.x), h2b = bf2f(u2.y);
            const float* wkA = wp + loc * 48;        // k = 2*loc   (wave-uniform)
            const float* wkB = wkA + 24;             // k = 2*loc+1
            #pragma unroll
            for (int c = 0; c < 8; ++c) {
                p1[c] += wkA[c] * h1a + wkB[c] * h1b;
                p2[c] += wkA[8 + c] * h1a + wkB[8 + c] * h1b
                       + wkA[16 + c] * h2a + wkB[16 + c] * h2b;
            }
        }
        #pragma unroll
        for (int c = 0; c < 8; ++c) {
            red[0][w][c][b] = p1[c];
            red[1][w][c][b] = p2[c];
        }
        float xv = (t < 128 && p < 512) ? bf2f(XT[p * 64 + b]) : 0.f;
        __syncthreads();
        if (t < 256) {
            bool active = (cell_l == 0) ? (p < 512) : (p >= 1);
            if (active) {
                const int c_i = cell_hu, c_j = 2 + cell_hu, c_f = 4 + cell_hu, c_o = 6 + cell_hu;
                float zi = bias_i, zj = bias_j, zf = bias_f, zo = bias_o;
                #pragma unroll
                for (int ww = 0; ww < 8; ++ww) {
                    zi += red[cell_l][ww][c_i][b];
                    zj += red[cell_l][ww][c_j][b];
                    zf += red[cell_l][ww][c_f][b];
                    zo += red[cell_l][ww][c_o][b];
                }
                if (cell_l == 0) {
                    zi += xv * wx_i; zj += xv * wx_j; zf += xv * wx_f; zo += xv * wx_o;
                }
                float c = cstate;
                c = c * sigm(zf + 1.f) + sigm(zi) * tanh_f(zj);
                cstate = c;
                float hn = tanh_f(c) * sigm(zo);
                unsigned short* Hn = (cell_l == 0 ? H1w : H2w) + ((p + 1) & 1) * 32768;
                Hn[(bx * 64 + b) * 2 + cell_hu] = f2bf(hn);
            }
        }
        grid_bar(BAR, p, bx, t);
    }
}

__global__ void logits_kernel(const char* __restrict__ wsb, const float* __restrict__ sw,
                              const float* __restrict__ sb, float* __restrict__ out) {
    const unsigned short* h2 = (const unsigned short*)(wsb + H2_BYTES) + 32768; // buf 1
    int c = blockIdx.x, b = threadIdx.x;
    float acc = 0.f;
    for (int k = 0; k < 512; ++k)
        acc += bf2f(h2[(k >> 1) * 128 + b * 2 + (k & 1)]) * sw[k * 10 + c];
    out[b * 10 + c] = acc + sb[c];
}

extern "C" void kernel_launch(void* const* d_in, const int* in_sizes, int n_in,
                              void* d_out, int out_size, void* d_ws, size_t ws_size,
                              hipStream_t stream) {
    (void)in_sizes; (void)n_in; (void)out_size; (void)ws_size;
    const float* x  = (const float*)d_in[0];
    const float* W0 = (const float*)d_in[1];
    const float* b0 = (const float*)d_in[2];
    const float* W1 = (const float*)d_in[3];
    const float* b1 = (const float*)d_in[4];
    const float* sw = (const float*)d_in[5];
    const float* sb = (const float*)d_in[6];
    char* wsb  = (char*)d_ws;
    float* out = (float*)d_out;

    hipLaunchKernelGGL(init_kernel, dim3(1024), dim3(256), 0, stream, x, W0, W1, wsb);

    char* wsb_p = wsb;
    const float* W0_p = W0;
    const float* b0_p = b0;
    const float* b1_p = b1;
    void* args[] = { &wsb_p, &W0_p, &b0_p, &b1_p };
    (void)hipLaunchCooperativeKernel((void*)lstm_kernel, dim3(256), dim3(512), args, 0, stream);

    hipLaunchKernelGGL(logits_kernel, dim3(10), dim3(64), 0, stream, wsb, sw, sb, out);
}

// Round 5
// 13952.768 us; speedup vs baseline: 2.3934x; 1.2892x over previous
//
#include <hip/hip_runtime.h>
#include <hip/hip_bf16.h>

// ws byte layout:
//   HH:  bf16 [2][256][64][4] @ 0       (262144 B)  h dbuf: per (k2,b) one 8B word =
//        {h1[2k2],h1[2k2+1],h2[2k2],h2[2k2+1]} — exchanged via agent-scope atomics (MALL)
//   XT:  bf16 [512][64]       @ 262144  (65536 B)   x transposed [t][b]
//   BAR: int  leaf[16] @ stride 128 B, root @ +2048  @ 327680
//   WP:  f32  [256][512][24]  @ 393216  (12.6 MB)   per-WG packed weights
//        WP[bx][k][c]  c=0..7: W0r col(c); 8..15: W1a col(c); 16..23: W1b col(c)
//        col(c) = (c>>1)*512 + bx*2 + (c&1)
#define HH_BYTES 0
#define XT_BYTES 262144
#define BAR_BYTES 327680
#define WP_BYTES 393216

__device__ __forceinline__ float sigm(float x) { return 1.f / (1.f + __expf(-x)); }
__device__ __forceinline__ float tanh_f(float x) {
    float a = fabsf(x);
    float e = __expf(-2.f * a);
    float r = (1.f - e) / (1.f + e);
    return copysignf(r, x);
}
__device__ __forceinline__ float bf2f(unsigned int u) {
    union { unsigned int i; float f; } v; v.i = u << 16; return v.f;
}
__device__ __forceinline__ unsigned short f2bf(float f) {
    union { float f; unsigned int i; } v; v.f = f;
    unsigned int u = v.i + 0x7fffu + ((v.i >> 16) & 1u);   // RNE
    return (unsigned short)(u >> 16);
}

__global__ void init_kernel(const float* __restrict__ x, const float* __restrict__ W0,
                            const float* __restrict__ W1, char* __restrict__ wsb) {
    unsigned int* HHz = (unsigned int*)(wsb + HH_BYTES);     // 65536 dwords
    unsigned short* XT = (unsigned short*)(wsb + XT_BYTES);
    int* BAR = (int*)(wsb + BAR_BYTES);
    float* WP = (float*)(wsb + WP_BYTES);
    int i = blockIdx.x * blockDim.x + threadIdx.x;
    int stride = gridDim.x * blockDim.x;
    for (int j = i; j < 65536; j += stride) HHz[j] = 0;
    for (int j = i; j < 32768; j += stride) {
        int p = j >> 6, b = j & 63;
        XT[j] = f2bf(x[b * 512 + p]);
    }
    for (int j = i; j < 17 * 32; j += stride) BAR[j] = 0;
    for (int j = i; j < 256 * 512 * 24; j += stride) {
        int c = j % 24;
        int r = j / 24;            // bx*512 + k
        int k = r & 511;
        int bx = r >> 9;
        int cc = c & 7;
        int col = ((cc >> 1) << 9) + bx * 2 + (cc & 1);
        int mat = c >> 3;
        float v;
        if (mat == 0)      v = W0[(1 + k) * 2048 + col];
        else if (mat == 1) v = W1[k * 2048 + col];
        else               v = W1[(512 + k) * 2048 + col];
        WP[j] = v;
    }
}

// No __threadfence: h + counters go through MALL via agent-scope atomics;
// __syncthreads' vmcnt(0) drain orders the sc-stores before the signal.
__device__ __forceinline__ void grid_bar(int* bar, int phase, int bx, int t) {
    __syncthreads();
    if (t == 0) {
        int* leaf = bar + (bx >> 4) * 32;
        int* root = bar + 16 * 32;
        int target = (phase + 1) * 16;
        int old = __hip_atomic_fetch_add(leaf, 1, __ATOMIC_RELAXED, __HIP_MEMORY_SCOPE_AGENT);
        if (old == target - 1)
            __hip_atomic_fetch_add(root, 1, __ATOMIC_RELAXED, __HIP_MEMORY_SCOPE_AGENT);
        while (__hip_atomic_load(root, __ATOMIC_RELAXED, __HIP_MEMORY_SCOPE_AGENT) < target)
            __builtin_amdgcn_s_sleep(1);
    }
    __syncthreads();
}

__global__ __launch_bounds__(512) void lstm_kernel(char* __restrict__ wsb,
        const float* __restrict__ W0, const float* __restrict__ b0,
        const float* __restrict__ b1) {
    __shared__ float red[2][8][8][64];   // [layer][wave][c][b], 32 KB

    const int t = threadIdx.x, bx = blockIdx.x;
    const int b = t & 63;
    const int w = __builtin_amdgcn_readfirstlane(t >> 6);    // wave id = k-slice owner

    const unsigned long long* HH = (const unsigned long long*)(wsb + HH_BYTES);
    unsigned int* HHw = (unsigned int*)(wsb + HH_BYTES);
    const unsigned short* XT = (const unsigned short*)(wsb + XT_BYTES);
    int* BAR = (int*)(wsb + BAR_BYTES);
    const float* wp = (const float*)(wsb + WP_BYTES)
                    + __builtin_amdgcn_readfirstlane(bx * 12288 + (t >> 6) * 1536);

    // cell threads: t<128 -> (layer l = t>>6, batch b); each computes BOTH hu of its pair
    const int cell_l = t >> 6;   // valid for t<128
    float cs0 = 0.f, cs1 = 0.f;
    float bi0 = 0, bi1 = 0, bj0 = 0, bj1 = 0, bf0 = 0, bf1 = 0, bo0 = 0, bo1 = 0;
    float wxi0 = 0, wxi1 = 0, wxj0 = 0, wxj1 = 0, wxf0 = 0, wxf1 = 0, wxo0 = 0, wxo1 = 0;
    if (t < 128) {
        int u0 = bx * 2, u1 = bx * 2 + 1;
        const float* bb = (cell_l == 0) ? b0 : b1;
        bi0 = bb[u0];            bi1 = bb[u1];
        bj0 = bb[512 + u0];      bj1 = bb[512 + u1];
        bf0 = bb[1024 + u0];     bf1 = bb[1024 + u1];
        bo0 = bb[1536 + u0];     bo1 = bb[1536 + u1];
        if (cell_l == 0) {
            wxi0 = W0[u0];          wxi1 = W0[u1];
            wxj0 = W0[512 + u0];    wxj1 = W0[512 + u1];
            wxf0 = W0[1024 + u0];   wxf1 = W0[1024 + u1];
            wxo0 = W0[1536 + u0];   wxo1 = W0[1536 + u1];
        }
    }

    for (int p = 0; p <= 512; ++p) {
        const unsigned long long* hp = HH + (p & 1) * 16384 + w * 2048 + b;
        float p1[8] = {0, 0, 0, 0, 0, 0, 0, 0};
        float p2[8] = {0, 0, 0, 0, 0, 0, 0, 0};
        #pragma unroll
        for (int half = 0; half < 2; ++half) {
            unsigned long long vv[16];
            #pragma unroll
            for (int i = 0; i < 16; ++i)
                vv[i] = __hip_atomic_load(hp + (half * 16 + i) * 64,
                                          __ATOMIC_RELAXED, __HIP_MEMORY_SCOPE_AGENT);
            #pragma unroll
            for (int i = 0; i < 16; ++i) {
                int loc = half * 16 + i;
                unsigned int lo = (unsigned int)vv[i];
                unsigned int hi = (unsigned int)(vv[i] >> 32);
                float h1a = bf2f(lo & 0xffffu), h1b = bf2f(lo >> 16);
                float h2a = bf2f(hi & 0xffffu), h2b = bf2f(hi >> 16);
                const float* wkA = wp + loc * 48;
                const float* wkB = wkA + 24;
                #pragma unroll
                for (int c = 0; c < 8; ++c) {
                    p1[c] += wkA[c] * h1a + wkB[c] * h1b;
                    p2[c] += wkA[8 + c] * h1a + wkB[8 + c] * h1b
                           + wkA[16 + c] * h2a + wkB[16 + c] * h2b;
                }
            }
        }
        #pragma unroll
        for (int c = 0; c < 8; ++c) {
            red[0][w][c][b] = p1[c];
            red[1][w][c][b] = p2[c];
        }
        float xv = (t < 64 && p < 512) ? bf2f((unsigned int)XT[p * 64 + b]) : 0.f;
        __syncthreads();
        if (t < 128) {
            bool active = (cell_l == 0) ? (p < 512) : (p >= 1);
            if (active) {
                float zi0 = bi0, zi1 = bi1, zj0 = bj0, zj1 = bj1;
                float zf0 = bf0, zf1 = bf1, zo0 = bo0, zo1 = bo1;
                #pragma unroll
                for (int ww = 0; ww < 8; ++ww) {
                    zi0 += red[cell_l][ww][0][b]; zi1 += red[cell_l][ww][1][b];
                    zj0 += red[cell_l][ww][2][b]; zj1 += red[cell_l][ww][3][b];
                    zf0 += red[cell_l][ww][4][b]; zf1 += red[cell_l][ww][5][b];
                    zo0 += red[cell_l][ww][6][b]; zo1 += red[cell_l][ww][7][b];
                }
                if (cell_l == 0) {
                    zi0 += xv * wxi0; zi1 += xv * wxi1;
                    zj0 += xv * wxj0; zj1 += xv * wxj1;
                    zf0 += xv * wxf0; zf1 += xv * wxf1;
                    zo0 += xv * wxo0; zo1 += xv * wxo1;
                }
                cs0 = cs0 * sigm(zf0 + 1.f) + sigm(zi0) * tanh_f(zj0);
                cs1 = cs1 * sigm(zf1 + 1.f) + sigm(zi1) * tanh_f(zj1);
                float h0 = tanh_f(cs0) * sigm(zo0);
                float h1 = tanh_f(cs1) * sigm(zo1);
                unsigned int packed = (unsigned int)f2bf(h0)
                                    | ((unsigned int)f2bf(h1) << 16);
                unsigned int* dst = HHw + (((p + 1) & 1) * 16384 + bx * 64 + b) * 2 + cell_l;
                __hip_atomic_store(dst, packed, __ATOMIC_RELAXED, __HIP_MEMORY_SCOPE_AGENT);
            }
        }
        grid_bar(BAR, p, bx, t);
    }
}

__global__ void logits_kernel(const char* __restrict__ wsb, const float* __restrict__ sw,
                              const float* __restrict__ sb, float* __restrict__ out) {
    const unsigned int* HHr = (const unsigned int*)(wsb + HH_BYTES);
    int c = blockIdx.x, b = threadIdx.x;
    float acc = 0.f;
    for (int k2 = 0; k2 < 256; ++k2) {
        unsigned int v = HHr[(16384 + k2 * 64 + b) * 2 + 1];   // buf1, layer2 half
        acc += bf2f(v & 0xffffu) * sw[(2 * k2) * 10 + c];
        acc += bf2f(v >> 16) * sw[(2 * k2 + 1) * 10 + c];
    }
    out[b * 10 + c] = acc + sb[c];
}

extern "C" void kernel_launch(void* const* d_in, const int* in_sizes, int n_in,
                              void* d_out, int out_size, void* d_ws, size_t ws_size,
                              hipStream_t stream) {
    (void)in_sizes; (void)n_in; (void)out_size; (void)ws_size;
    const float* x  = (const float*)d_in[0];
    const float* W0 = (const float*)d_in[1];
    const float* b0 = (const float*)d_in[2];
    const float* W1 = (const float*)d_in[3];
    const float* b1 = (const float*)d_in[4];
    const float* sw = (const float*)d_in[5];
    const float* sb = (const float*)d_in[6];
    char* wsb  = (char*)d_ws;
    float* out = (float*)d_out;

    hipLaunchKernelGGL(init_kernel, dim3(1024), dim3(256), 0, stream, x, W0, W1, wsb);

    char* wsb_p = wsb;
    const float* W0_p = W0;
    const float* b0_p = b0;
    const float* b1_p = b1;
    void* args[] = { &wsb_p, &W0_p, &b0_p, &b1_p };
    (void)hipLaunchCooperativeKernel((void*)lstm_kernel, dim3(256), dim3(512), args, 0, stream);

    hipLaunchKernelGGL(logits_kernel, dim3(10), dim3(64), 0, stream, wsb, sw, sb, out);
}

// Round 6
// 13029.839 us; speedup vs baseline: 2.5630x; 1.0708x over previous
//
#include <hip/hip_runtime.h>
#include <hip/hip_bf16.h>

// ws byte layout:
//   HH:  bf16 [2][256][64][4] @ 0       (262144 B)  h dbuf: per (k2,b) one 8B word =
//        {h1[2k2],h1[2k2+1],h2[2k2],h2[2k2+1]} — exchanged via agent-scope atomics (MALL)
//   XT:  bf16 [512][64]       @ 262144  (65536 B)   x transposed [t][b]
//   BAR: @ 327680  ints, 128B-strided slots:
//        leaf[i]  = BAR + i*32        (i=0..15; 16 WGs/leaf)
//        root     = BAR + 16*32
//        mail[w]  = BAR + (17+w)*32   (w=0..255; per-WG mailbox, 1 poller each)
//   WP:  f32  [256][512][24]  @ 393216  (12.6 MB)   per-WG packed weights
//        WP[bx][k][c]  c=0..7: W0r col(c); 8..15: W1a col(c); 16..23: W1b col(c)
//        col(c) = (c>>1)*512 + bx*2 + (c&1)
#define HH_BYTES 0
#define XT_BYTES 262144
#define BAR_BYTES 327680
#define WP_BYTES 393216
#define BAR_INTS (273 * 32)

__device__ __forceinline__ float sigm(float x) { return 1.f / (1.f + __expf(-x)); }
__device__ __forceinline__ float tanh_f(float x) {
    float a = fabsf(x);
    float e = __expf(-2.f * a);
    float r = (1.f - e) / (1.f + e);
    return copysignf(r, x);
}
__device__ __forceinline__ float bf2f(unsigned int u) {
    union { unsigned int i; float f; } v; v.i = u << 16; return v.f;
}
__device__ __forceinline__ unsigned short f2bf(float f) {
    union { float f; unsigned int i; } v; v.f = f;
    unsigned int u = v.i + 0x7fffu + ((v.i >> 16) & 1u);   // RNE
    return (unsigned short)(u >> 16);
}

__global__ void init_kernel(const float* __restrict__ x, const float* __restrict__ W0,
                            const float* __restrict__ W1, char* __restrict__ wsb) {
    unsigned int* HHz = (unsigned int*)(wsb + HH_BYTES);     // 65536 dwords
    unsigned short* XT = (unsigned short*)(wsb + XT_BYTES);
    int* BAR = (int*)(wsb + BAR_BYTES);
    float* WP = (float*)(wsb + WP_BYTES);
    int i = blockIdx.x * blockDim.x + threadIdx.x;
    int stride = gridDim.x * blockDim.x;
    for (int j = i; j < 65536; j += stride) HHz[j] = 0;
    for (int j = i; j < 32768; j += stride) {
        int p = j >> 6, b = j & 63;
        XT[j] = f2bf(x[b * 512 + p]);
    }
    for (int j = i; j < BAR_INTS; j += stride) BAR[j] = 0;
    for (int j = i; j < 256 * 512 * 24; j += stride) {
        int c = j % 24;
        int r = j / 24;            // bx*512 + k
        int k = r & 511;
        int bx = r >> 9;
        int cc = c & 7;
        int col = ((cc >> 1) << 9) + bx * 2 + (cc & 1);
        int mat = c >> 3;
        float v;
        if (mat == 0)      v = W0[(1 + k) * 2048 + col];
        else if (mat == 1) v = W1[k * 2048 + col];
        else               v = W1[(512 + k) * 2048 + col];
        WP[j] = v;
    }
}

// Fan-out barrier: leaf RMW (16/line) -> root RMW (16/line) -> broadcaster wave
// stores per-WG mailboxes (256 lines, 1 poller each). No single-address poll
// hot-spot. No fences: h + counters all go through MALL via agent-scope ops;
// per-wave vmcnt(0) drain at __syncthreads orders h-stores before the signal.
__device__ __forceinline__ void grid_bar(int* bar, int phase, int bx, int t) {
    __syncthreads();
    if (t < 64) {
        int* leaf = bar + (bx >> 4) * 32;
        int* root = bar + 16 * 32;
        int* mailbase = bar + 17 * 32;
        int target = 16 * (phase + 1);
        int isB = 0;
        if (t == 0) {
            int old = __hip_atomic_fetch_add(leaf, 1, __ATOMIC_RELAXED, __HIP_MEMORY_SCOPE_AGENT);
            if (old == target - 1) {
                int ro = __hip_atomic_fetch_add(root, 1, __ATOMIC_RELAXED, __HIP_MEMORY_SCOPE_AGENT);
                if (ro == target - 1) isB = 1;
            }
        }
        isB = __builtin_amdgcn_readfirstlane(isB);
        if (isB) {
            #pragma unroll
            for (int r = 0; r < 4; ++r)
                __hip_atomic_store(mailbase + (r * 64 + t) * 32, phase + 1,
                                   __ATOMIC_RELAXED, __HIP_MEMORY_SCOPE_AGENT);
        }
        if (t == 0) {
            int* my = mailbase + bx * 32;
            while (__hip_atomic_load(my, __ATOMIC_RELAXED, __HIP_MEMORY_SCOPE_AGENT) < phase + 1)
                __builtin_amdgcn_s_sleep(1);
        }
    }
    __syncthreads();
}

__global__ __launch_bounds__(512) void lstm_kernel(char* __restrict__ wsb,
        const float* __restrict__ W0, const float* __restrict__ b0,
        const float* __restrict__ b1) {
    __shared__ float red[2][8][8][64];   // [layer][wave][c][b], 32 KB

    const int t = threadIdx.x, bx = blockIdx.x;
    const int b = t & 63;
    const int w = __builtin_amdgcn_readfirstlane(t >> 6);    // wave id = k-slice owner

    const unsigned long long* HH = (const unsigned long long*)(wsb + HH_BYTES);
    unsigned int* HHw = (unsigned int*)(wsb + HH_BYTES);
    const unsigned short* XT = (const unsigned short*)(wsb + XT_BYTES);
    int* BAR = (int*)(wsb + BAR_BYTES);
    const float* wp = (const float*)(wsb + WP_BYTES)
                    + __builtin_amdgcn_readfirstlane(bx * 12288 + (t >> 6) * 1536);

    // cell threads: t<128 -> (layer l = t>>6, batch b); each computes BOTH hu of its pair
    const int cell_l = t >> 6;   // valid for t<128
    float cs0 = 0.f, cs1 = 0.f;
    float bi0 = 0, bi1 = 0, bj0 = 0, bj1 = 0, bf0 = 0, bf1 = 0, bo0 = 0, bo1 = 0;
    float wxi0 = 0, wxi1 = 0, wxj0 = 0, wxj1 = 0, wxf0 = 0, wxf1 = 0, wxo0 = 0, wxo1 = 0;
    if (t < 128) {
        int u0 = bx * 2, u1 = bx * 2 + 1;
        const float* bb = (cell_l == 0) ? b0 : b1;
        bi0 = bb[u0];            bi1 = bb[u1];
        bj0 = bb[512 + u0];      bj1 = bb[512 + u1];
        bf0 = bb[1024 + u0];     bf1 = bb[1024 + u1];
        bo0 = bb[1536 + u0];     bo1 = bb[1536 + u1];
        if (cell_l == 0) {
            wxi0 = W0[u0];          wxi1 = W0[u1];
            wxj0 = W0[512 + u0];    wxj1 = W0[512 + u1];
            wxf0 = W0[1024 + u0];   wxf1 = W0[1024 + u1];
            wxo0 = W0[1536 + u0];   wxo1 = W0[1536 + u1];
        }
    }

    for (int p = 0; p <= 512; ++p) {
        const unsigned long long* hp = HH + (p & 1) * 16384 + w * 2048 + b;
        float p1[8] = {0, 0, 0, 0, 0, 0, 0, 0};
        float p2[8] = {0, 0, 0, 0, 0, 0, 0, 0};
        #pragma unroll
        for (int half = 0; half < 2; ++half) {
            unsigned long long vv[16];
            #pragma unroll
            for (int i = 0; i < 16; ++i)
                vv[i] = __hip_atomic_load(hp + (half * 16 + i) * 64,
                                          __ATOMIC_RELAXED, __HIP_MEMORY_SCOPE_AGENT);
            #pragma unroll
            for (int i = 0; i < 16; ++i) {
                int loc = half * 16 + i;
                unsigned int lo = (unsigned int)vv[i];
                unsigned int hi = (unsigned int)(vv[i] >> 32);
                float h1a = bf2f(lo & 0xffffu), h1b = bf2f(lo >> 16);
                float h2a = bf2f(hi & 0xffffu), h2b = bf2f(hi >> 16);
                const float* wkA = wp + loc * 48;
                const float* wkB = wkA + 24;
                #pragma unroll
                for (int c = 0; c < 8; ++c) {
                    p1[c] += wkA[c] * h1a + wkB[c] * h1b;
                    p2[c] += wkA[8 + c] * h1a + wkB[8 + c] * h1b
                           + wkA[16 + c] * h2a + wkB[16 + c] * h2b;
                }
            }
        }
        #pragma unroll
        for (int c = 0; c < 8; ++c) {
            red[0][w][c][b] = p1[c];
            red[1][w][c][b] = p2[c];
        }
        float xv = (t < 64 && p < 512) ? bf2f((unsigned int)XT[p * 64 + b]) : 0.f;
        __syncthreads();
        if (t < 128) {
            bool active = (cell_l == 0) ? (p < 512) : (p >= 1);
            if (active) {
                float zi0 = bi0, zi1 = bi1, zj0 = bj0, zj1 = bj1;
                float zf0 = bf0, zf1 = bf1, zo0 = bo0, zo1 = bo1;
                #pragma unroll
                for (int ww = 0; ww < 8; ++ww) {
                    zi0 += red[cell_l][ww][0][b]; zi1 += red[cell_l][ww][1][b];
                    zj0 += red[cell_l][ww][2][b]; zj1 += red[cell_l][ww][3][b];
                    zf0 += red[cell_l][ww][4][b]; zf1 += red[cell_l][ww][5][b];
                    zo0 += red[cell_l][ww][6][b]; zo1 += red[cell_l][ww][7][b];
                }
                if (cell_l == 0) {
                    zi0 += xv * wxi0; zi1 += xv * wxi1;
                    zj0 += xv * wxj0; zj1 += xv * wxj1;
                    zf0 += xv * wxf0; zf1 += xv * wxf1;
                    zo0 += xv * wxo0; zo1 += xv * wxo1;
                }
                cs0 = cs0 * sigm(zf0 + 1.f) + sigm(zi0) * tanh_f(zj0);
                cs1 = cs1 * sigm(zf1 + 1.f) + sigm(zi1) * tanh_f(zj1);
                float h0 = tanh_f(cs0) * sigm(zo0);
                float h1 = tanh_f(cs1) * sigm(zo1);
                unsigned int packed = (unsigned int)f2bf(h0)
                                    | ((unsigned int)f2bf(h1) << 16);
                unsigned int* dst = HHw + (((p + 1) & 1) * 16384 + bx * 64 + b) * 2 + cell_l;
                __hip_atomic_store(dst, packed, __ATOMIC_RELAXED, __HIP_MEMORY_SCOPE_AGENT);
            }
        }
        grid_bar(BAR, p, bx, t);
    }
}

__global__ void logits_kernel(const char* __restrict__ wsb, const float* __restrict__ sw,
                              const float* __restrict__ sb, float* __restrict__ out) {
    const unsigned int* HHr = (const unsigned int*)(wsb + HH_BYTES);
    int c = blockIdx.x, b = threadIdx.x;
    float acc = 0.f;
    for (int k2 = 0; k2 < 256; ++k2) {
        unsigned int v = HHr[(16384 + k2 * 64 + b) * 2 + 1];   // buf1, layer2 half
        acc += bf2f(v & 0xffffu) * sw[(2 * k2) * 10 + c];
        acc += bf2f(v >> 16) * sw[(2 * k2 + 1) * 10 + c];
    }
    out[b * 10 + c] = acc + sb[c];
}

extern "C" void kernel_launch(void* const* d_in, const int* in_sizes, int n_in,
                              void* d_out, int out_size, void* d_ws, size_t ws_size,
                              hipStream_t stream) {
    (void)in_sizes; (void)n_in; (void)out_size; (void)ws_size;
    const float* x  = (const float*)d_in[0];
    const float* W0 = (const float*)d_in[1];
    const float* b0 = (const float*)d_in[2];
    const float* W1 = (const float*)d_in[3];
    const float* b1 = (const float*)d_in[4];
    const float* sw = (const float*)d_in[5];
    const float* sb = (const float*)d_in[6];
    char* wsb  = (char*)d_ws;
    float* out = (float*)d_out;

    hipLaunchKernelGGL(init_kernel, dim3(1024), dim3(256), 0, stream, x, W0, W1, wsb);

    char* wsb_p = wsb;
    const float* W0_p = W0;
    const float* b0_p = b0;
    const float* b1_p = b1;
    void* args[] = { &wsb_p, &W0_p, &b0_p, &b1_p };
    (void)hipLaunchCooperativeKernel((void*)lstm_kernel, dim3(256), dim3(512), args, 0, stream);

    hipLaunchKernelGGL(logits_kernel, dim3(10), dim3(64), 0, stream, wsb, sw, sb, out);
}

// Round 7
// 12629.973 us; speedup vs baseline: 2.6441x; 1.0317x over previous
//
#include <hip/hip_runtime.h>
#include <hip/hip_bf16.h>

// ws byte layout:
//   HH:  bf16 [2][128][64][8] @ 0      (262144 B)  h dbuf: per (k4,b) one 16B word =
//        {h1[4k4..4k4+3], h2[4k4..4k4+3]} — written via agent-scope atomics,
//        read via inline-asm global_load_dwordx4 sc0 sc1 (MALL-coherent, batched)
//   XT:  bf16 [512][64]       @ 262144 (65536 B)   x transposed [t][b]
//   BAR: @ 327680  ints, 128B-strided slots:
//        leaf[i]  = BAR + i*32        (i=0..15; 16 WGs/leaf)
//        root     = BAR + 16*32
//        mail[w]  = BAR + (17+w)*32   (w=0..255; per-WG mailbox, 1 poller each)
//   WP:  f32  [256][128][4][24] @ 393216 (12.6 MB) per-WG packed weights:
//        WP[bx][k4][j][c]  (k=4*k4+j)  c=0..7: W0r col(c); 8..15: W1a; 16..23: W1b
//        col(c) = (c>>1)*512 + bx*2 + (c&1)
#define HH_BYTES 0
#define XT_BYTES 262144
#define BAR_BYTES 327680
#define WP_BYTES 393216
#define BAR_INTS (273 * 32)

typedef __attribute__((ext_vector_type(4))) unsigned int uint4v;

__device__ __forceinline__ float sigm(float x) { return 1.f / (1.f + __expf(-x)); }
__device__ __forceinline__ float tanh_f(float x) {
    float a = fabsf(x);
    float e = __expf(-2.f * a);
    float r = (1.f - e) / (1.f + e);
    return copysignf(r, x);
}
__device__ __forceinline__ float bf2f(unsigned int u) {
    union { unsigned int i; float f; } v; v.i = u << 16; return v.f;
}
__device__ __forceinline__ unsigned short f2bf(float f) {
    union { float f; unsigned int i; } v; v.f = f;
    unsigned int u = v.i + 0x7fffu + ((v.i >> 16) & 1u);   // RNE
    return (unsigned short)(u >> 16);
}

__global__ void init_kernel(const float* __restrict__ x, const float* __restrict__ W0,
                            const float* __restrict__ W1, char* __restrict__ wsb) {
    unsigned int* HHz = (unsigned int*)(wsb + HH_BYTES);     // 65536 dwords
    unsigned short* XT = (unsigned short*)(wsb + XT_BYTES);
    int* BAR = (int*)(wsb + BAR_BYTES);
    float* WP = (float*)(wsb + WP_BYTES);
    int i = blockIdx.x * blockDim.x + threadIdx.x;
    int stride = gridDim.x * blockDim.x;
    for (int j = i; j < 65536; j += stride) HHz[j] = 0;
    for (int j = i; j < 32768; j += stride) {
        int p = j >> 6, b = j & 63;
        XT[j] = f2bf(x[b * 512 + p]);
    }
    for (int j = i; j < BAR_INTS; j += stride) BAR[j] = 0;
    for (int j = i; j < 256 * 512 * 24; j += stride) {
        int c = j % 24;
        int r = j / 24;            // bx*512 + k   (k = 4*k4 + subk)
        int k = r & 511;
        int bx = r >> 9;
        int cc = c & 7;
        int col = ((cc >> 1) << 9) + bx * 2 + (cc & 1);
        int mat = c >> 3;
        float v;
        if (mat == 0)      v = W0[(1 + k) * 2048 + col];
        else if (mat == 1) v = W1[k * 2048 + col];
        else               v = W1[(512 + k) * 2048 + col];
        WP[j] = v;
    }
}

// Fan-out barrier (R6): leaf RMW -> root RMW -> broadcaster stores 256 per-WG
// mailboxes (1 poller/line). All counters MALL-resident via agent-scope atomics.
__device__ __forceinline__ void grid_bar(int* bar, int phase, int bx, int t) {
    __syncthreads();
    if (t < 64) {
        int* leaf = bar + (bx >> 4) * 32;
        int* root = bar + 16 * 32;
        int* mailbase = bar + 17 * 32;
        int target = 16 * (phase + 1);
        int isB = 0;
        if (t == 0) {
            int old = __hip_atomic_fetch_add(leaf, 1, __ATOMIC_RELAXED, __HIP_MEMORY_SCOPE_AGENT);
            if (old == target - 1) {
                int ro = __hip_atomic_fetch_add(root, 1, __ATOMIC_RELAXED, __HIP_MEMORY_SCOPE_AGENT);
                if (ro == target - 1) isB = 1;
            }
        }
        isB = __builtin_amdgcn_readfirstlane(isB);
        if (isB) {
            #pragma unroll
            for (int r = 0; r < 4; ++r)
                __hip_atomic_store(mailbase + (r * 64 + t) * 32, phase + 1,
                                   __ATOMIC_RELAXED, __HIP_MEMORY_SCOPE_AGENT);
        }
        if (t == 0) {
            int* my = mailbase + bx * 32;
            while (__hip_atomic_load(my, __ATOMIC_RELAXED, __HIP_MEMORY_SCOPE_AGENT) < phase + 1)
                __builtin_amdgcn_s_sleep(1);
        }
    }
    __syncthreads();
}

__global__ __launch_bounds__(512) void lstm_kernel(char* __restrict__ wsb,
        const float* __restrict__ W0, const float* __restrict__ b0,
        const float* __restrict__ b1) {
    __shared__ float red[2][8][8][64];   // [layer][wave][c][b], 32 KB

    const int t = threadIdx.x, bx = blockIdx.x;
    const int b = t & 63;
    const int w = __builtin_amdgcn_readfirstlane(t >> 6);    // wave id = k-slice owner

    const uint4v* HH = (const uint4v*)(wsb + HH_BYTES);      // 16B words
    unsigned int* HHw = (unsigned int*)(wsb + HH_BYTES);
    const unsigned short* XT = (const unsigned short*)(wsb + XT_BYTES);
    int* BAR = (int*)(wsb + BAR_BYTES);
    const float* wp = (const float*)(wsb + WP_BYTES)
                    + __builtin_amdgcn_readfirstlane(bx * 12288 + (t >> 6) * 1536);

    // cell threads: t<128 -> (layer l = t>>6, batch b); each computes BOTH hu of its pair
    const int cell_l = t >> 6;   // valid for t<128
    float cs0 = 0.f, cs1 = 0.f;
    float bi0 = 0, bi1 = 0, bj0 = 0, bj1 = 0, bf0 = 0, bf1 = 0, bo0 = 0, bo1 = 0;
    float wxi0 = 0, wxi1 = 0, wxj0 = 0, wxj1 = 0, wxf0 = 0, wxf1 = 0, wxo0 = 0, wxo1 = 0;
    if (t < 128) {
        int u0 = bx * 2, u1 = bx * 2 + 1;
        const float* bb = (cell_l == 0) ? b0 : b1;
        bi0 = bb[u0];            bi1 = bb[u1];
        bj0 = bb[512 + u0];      bj1 = bb[512 + u1];
        bf0 = bb[1024 + u0];     bf1 = bb[1024 + u1];
        bo0 = bb[1536 + u0];     bo1 = bb[1536 + u1];
        if (cell_l == 0) {
            wxi0 = W0[u0];          wxi1 = W0[u1];
            wxj0 = W0[512 + u0];    wxj1 = W0[512 + u1];
            wxf0 = W0[1024 + u0];   wxf1 = W0[1024 + u1];
            wxo0 = W0[1536 + u0];   wxo1 = W0[1536 + u1];
        }
    }

    for (int p = 0; p <= 512; ++p) {
        // k4 = w*16 + i; word address (16B units): buf*8192 + k4*64 + b
        const uint4v* hp = HH + (p & 1) * 8192 + w * 1024 + b;
        float p1[8] = {0, 0, 0, 0, 0, 0, 0, 0};
        float p2[8] = {0, 0, 0, 0, 0, 0, 0, 0};

        // Batched coherent loads: 16 in flight, ONE vmcnt(0). sc0 sc1 = bypass
        // L1/L2, serviced at MALL (same coherence point the sc-stores drain to).
        uint4v vv[16];
        #pragma unroll
        for (int i = 0; i < 16; ++i)
            asm volatile("global_load_dwordx4 %0, %1, off sc0 sc1"
                         : "=v"(vv[i]) : "v"(hp + i * 64));
        asm volatile("s_waitcnt vmcnt(0)" ::: "memory");

        #pragma unroll
        for (int i = 0; i < 16; ++i) {
            unsigned int x0 = vv[i].x, x1 = vv[i].y, x2 = vv[i].z, x3 = vv[i].w;
            float h1v[4] = { bf2f(x0 & 0xffffu), bf2f(x0 >> 16),
                             bf2f(x1 & 0xffffu), bf2f(x1 >> 16) };
            float h2v[4] = { bf2f(x2 & 0xffffu), bf2f(x2 >> 16),
                             bf2f(x3 & 0xffffu), bf2f(x3 >> 16) };
            const float* wk = wp + i * 96;          // wave-uniform -> s_load
            #pragma unroll
            for (int j = 0; j < 4; ++j) {
                const float* wj = wk + j * 24;
                #pragma unroll
                for (int c = 0; c < 8; ++c) {
                    p1[c] += wj[c] * h1v[j];
                    p2[c] += wj[8 + c] * h1v[j] + wj[16 + c] * h2v[j];
                }
            }
        }
        #pragma unroll
        for (int c = 0; c < 8; ++c) {
            red[0][w][c][b] = p1[c];
            red[1][w][c][b] = p2[c];
        }
        float xv = (t < 64 && p < 512) ? bf2f((unsigned int)XT[p * 64 + b]) : 0.f;
        __syncthreads();
        if (t < 128) {
            bool active = (cell_l == 0) ? (p < 512) : (p >= 1);
            if (active) {
                float zi0 = bi0, zi1 = bi1, zj0 = bj0, zj1 = bj1;
                float zf0 = bf0, zf1 = bf1, zo0 = bo0, zo1 = bo1;
                #pragma unroll
                for (int ww = 0; ww < 8; ++ww) {
                    zi0 += red[cell_l][ww][0][b]; zi1 += red[cell_l][ww][1][b];
                    zj0 += red[cell_l][ww][2][b]; zj1 += red[cell_l][ww][3][b];
                    zf0 += red[cell_l][ww][4][b]; zf1 += red[cell_l][ww][5][b];
                    zo0 += red[cell_l][ww][6][b]; zo1 += red[cell_l][ww][7][b];
                }
                if (cell_l == 0) {
                    zi0 += xv * wxi0; zi1 += xv * wxi1;
                    zj0 += xv * wxj0; zj1 += xv * wxj1;
                    zf0 += xv * wxf0; zf1 += xv * wxf1;
                    zo0 += xv * wxo0; zo1 += xv * wxo1;
                }
                cs0 = cs0 * sigm(zf0 + 1.f) + sigm(zi0) * tanh_f(zj0);
                cs1 = cs1 * sigm(zf1 + 1.f) + sigm(zi1) * tanh_f(zj1);
                float h0 = tanh_f(cs0) * sigm(zo0);
                float h1 = tanh_f(cs1) * sigm(zo1);
                unsigned int packed = (unsigned int)f2bf(h0)
                                    | ((unsigned int)f2bf(h1) << 16);
                // word (bx>>1, b), dword (cell_l*2 + (bx&1))
                unsigned int* dst = HHw + (((p + 1) & 1) * 8192 + (bx >> 1) * 64 + b) * 4
                                  + cell_l * 2 + (bx & 1);
                __hip_atomic_store(dst, packed, __ATOMIC_RELAXED, __HIP_MEMORY_SCOPE_AGENT);
            }
        }
        grid_bar(BAR, p, bx, t);
    }
}

__global__ void logits_kernel(const char* __restrict__ wsb, const float* __restrict__ sw,
                              const float* __restrict__ sb, float* __restrict__ out) {
    const unsigned int* HHr = (const unsigned int*)(wsb + HH_BYTES);
    int c = blockIdx.x, b = threadIdx.x;
    float acc = 0.f;
    for (int k4 = 0; k4 < 128; ++k4) {
        int base = (8192 + k4 * 64 + b) * 4;       // buf 1
        unsigned int u = HHr[base + 2];            // h2[4k4], h2[4k4+1]
        unsigned int v = HHr[base + 3];            // h2[4k4+2], h2[4k4+3]
        acc += bf2f(u & 0xffffu) * sw[(4 * k4 + 0) * 10 + c];
        acc += bf2f(u >> 16)     * sw[(4 * k4 + 1) * 10 + c];
        acc += bf2f(v & 0xffffu) * sw[(4 * k4 + 2) * 10 + c];
        acc += bf2f(v >> 16)     * sw[(4 * k4 + 3) * 10 + c];
    }
    out[b * 10 + c] = acc + sb[c];
}

extern "C" void kernel_launch(void* const* d_in, const int* in_sizes, int n_in,
                              void* d_out, int out_size, void* d_ws, size_t ws_size,
                              hipStream_t stream) {
    (void)in_sizes; (void)n_in; (void)out_size; (void)ws_size;
    const float* x  = (const float*)d_in[0];
    const float* W0 = (const float*)d_in[1];
    const float* b0 = (const float*)d_in[2];
    const float* W1 = (const float*)d_in[3];
    const float* b1 = (const float*)d_in[4];
    const float* sw = (const float*)d_in[5];
    const float* sb = (const float*)d_in[6];
    char* wsb  = (char*)d_ws;
    float* out = (float*)d_out;

    hipLaunchKernelGGL(init_kernel, dim3(1024), dim3(256), 0, stream, x, W0, W1, wsb);

    char* wsb_p = wsb;
    const float* W0_p = W0;
    const float* b0_p = b0;
    const float* b1_p = b1;
    void* args[] = { &wsb_p, &W0_p, &b0_p, &b1_p };
    (void)hipLaunchCooperativeKernel((void*)lstm_kernel, dim3(256), dim3(512), args, 0, stream);

    hipLaunchKernelGGL(logits_kernel, dim3(10), dim3(64), 0, stream, wsb, sw, sb, out);
}